// Round 6
// baseline (2401.778 us; speedup 1.0000x reference)
//
#include <hip/hip_runtime.h>
#include <math.h>

#define TT 256
#define FF 64
#define HH 20
#define G4 80    // 4*H
#define EPB 4    // batch elems per block
#define BLK 960  // 5 waves L1 | 5 waves L2 | 5 waves PROJ

__device__ __forceinline__ float sigmoidf_(float z) {
    return 1.0f / (1.0f + __expf(-z));
}

// quad_perm DPP: value from lane (lane ^ m) within each aligned quad (VALU, no DS)
__device__ __forceinline__ float qpx1(float v) {
    return __int_as_float(__builtin_amdgcn_mov_dpp(__float_as_int(v), 0xB1, 0xF, 0xF, true));
}
__device__ __forceinline__ float qpx2(float v) {
    return __int_as_float(__builtin_amdgcn_mov_dpp(__float_as_int(v), 0x4E, 0xF, 0xF, true));
}
__device__ __forceinline__ float qpx3(float v) {
    return __int_as_float(__builtin_amdgcn_mov_dpp(__float_as_int(v), 0x1B, 0xF, 0xF, true));
}

// ===== Fused: PROJ waves feed an LDS ring; L1/L2 producer-consumer; 1 barrier/step =====
// role 0 (tid<320):  layer-1 recurrence; thread=(elem, col via quad layout)
// role 1 (tid<640):  layer-2 recurrence, one step behind L1
// role 2 (tid<960):  xw(t+2) = b1 + x(t+2)@W1 into ring[(t+2)&3]; thread=(elem, col direct)
// Ring hazards: slot s written at iter s-2, read at iter s, rewritten at iter s+2
//   -> every pair separated by >=1 __syncthreads(). Prologue fills slots 0,1.
__global__ __launch_bounds__(BLK, 8) void lstm2_fused3(
    const float* __restrict__ x,
    const float* __restrict__ W1, const float* __restrict__ U1, const float* __restrict__ b1,
    const float* __restrict__ W2, const float* __restrict__ U2, const float* __restrict__ b2,
    const float* __restrict__ Wd, const float* __restrict__ bd,
    float* __restrict__ out, int B)
{
    const int tid  = threadIdx.x;
    const int role = tid / 320;          // wave-uniform (320 = 5 waves)
    const int rt   = tid - role * 320;
    const int elem = rt / G4;            // 0..3
    const int j    = rt - elem * G4;     // 0..79
    const int g    = j & 3;              // gate: 0=i 1=f 2=c 3=o   (roles 0/1)
    const int u    = j >> 2;             // unit 0..19              (roles 0/1)
    const int col  = g * HH + u;         // weight column           (roles 0/1)
    const int b0   = blockIdx.x * EPB;

    __shared__ float h1b[2][EPB][24];
    __shared__ float h2b[2][EPB][24];
    __shared__ float ring[4][EPB][G4];   // xw ring, depth 4

    // ---- per-role weights ----
    float wA[HH], wB[HH];    // L1: U1 col | L2: W2 col, U2 col
    float w1r[FF];           // PROJ: W1 column
    float bias = 0.f;        // L2 b2 / PROJ b1
    const float* xrow = nullptr;

    if (role == 0) {
#pragma unroll
        for (int k = 0; k < HH; ++k) wA[k] = U1[k * G4 + col];
    } else if (role == 1) {
#pragma unroll
        for (int k = 0; k < HH; ++k) wA[k] = W2[k * G4 + col];
#pragma unroll
        for (int k = 0; k < HH; ++k) wB[k] = U2[k * G4 + col];
        bias = b2[col];
    } else {
#pragma unroll
        for (int f = 0; f < FF; ++f) w1r[f] = W1[f * G4 + j];
        bias = b1[j];
        xrow = x + (size_t)(b0 + elem) * TT * FF;
    }

    // zero h buffers
    for (int i = tid; i < 2 * EPB * 24; i += BLK) ((float*)h1b)[i] = 0.f;
    for (int i = tid; i < 2 * EPB * 24; i += BLK) ((float*)h2b)[i] = 0.f;

    // PROJ prologue: fill ring slots 0,1 (xw at t=0,1)
    if (role == 2) {
#pragma unroll
        for (int tp = 0; tp < 2; ++tp) {
            const float4* xr = (const float4*)(xrow + (size_t)tp * FF);
            float a0 = 0.f, a1 = 0.f, a2 = 0.f, a3 = 0.f;
#pragma unroll
            for (int q = 0; q < FF / 4; ++q) {
                float4 xx = xr[q];
                a0 = fmaf(xx.x, w1r[4*q+0], a0);
                a1 = fmaf(xx.y, w1r[4*q+1], a1);
                a2 = fmaf(xx.z, w1r[4*q+2], a2);
                a3 = fmaf(xx.w, w1r[4*q+3], a3);
            }
            ring[tp][elem][j] = bias + ((a0 + a1) + (a2 + a3));
        }
    }

    float c1 = 0.f, c2 = 0.f;
    __syncthreads();

    for (int i = 0; i <= TT; ++i) {
        const int rb = (i + 1) & 1;      // read h buffers
        const int wb = i & 1;            // write h buffers

        if (role == 0) {
            if (i < TT) {
                // z = xw(i) + h1(i-1) @ U1
                float xwc = ring[i & 3][elem][col];
                float zz0 = 0.f, zz1 = 0.f, zz2 = 0.f, zz3 = 0.f;
                const float4* hv = (const float4*)h1b[rb][elem];
#pragma unroll
                for (int q = 0; q < HH / 4; ++q) {
                    float4 hh = hv[q];
                    zz0 = fmaf(hh.x, wA[4*q+0], zz0);
                    zz1 = fmaf(hh.y, wA[4*q+1], zz1);
                    zz2 = fmaf(hh.z, wA[4*q+2], zz2);
                    zz3 = fmaf(hh.w, wA[4*q+3], zz3);
                }
                float z = xwc + ((zz0 + zz1) + (zz2 + zz3));

                float a = (g == 2) ? fmaxf(z, 0.f) : sigmoidf_(z);
                float a1 = qpx1(a), a2 = qpx2(a), a3 = qpx3(a);
                // valid in g==0 lanes: i=a, f=a1, c=a2, o=a3
                c1 = a1 * c1 + a * a2;
                float h1n = a3 * fmaxf(c1, 0.f);
                if (g == 0) h1b[wb][elem][u] = h1n;
            }
        } else if (role == 1) {
            if (i >= 1) {
                // z2 = b2 + h1(i-1) @ W2 + h2(i-2) @ U2
                float y0 = 0.f, y1 = 0.f, y2 = 0.f, y3 = 0.f;
                const float4* h1v = (const float4*)h1b[rb][elem];
                const float4* h2v = (const float4*)h2b[rb][elem];
#pragma unroll
                for (int q = 0; q < HH / 4; ++q) {
                    float4 ha = h1v[q];
                    float4 hb = h2v[q];
                    y0 = fmaf(ha.x, wA[4*q+0], y0);
                    y1 = fmaf(ha.y, wA[4*q+1], y1);
                    y2 = fmaf(ha.z, wA[4*q+2], y2);
                    y3 = fmaf(ha.w, wA[4*q+3], y3);
                    y0 = fmaf(hb.x, wB[4*q+0], y0);
                    y1 = fmaf(hb.y, wB[4*q+1], y1);
                    y2 = fmaf(hb.z, wB[4*q+2], y2);
                    y3 = fmaf(hb.w, wB[4*q+3], y3);
                }
                float z2v = bias + ((y0 + y1) + (y2 + y3));

                float bgt = (g == 2) ? fmaxf(z2v, 0.f) : sigmoidf_(z2v);
                float b1_ = qpx1(bgt), b2_ = qpx2(bgt), b3_ = qpx3(bgt);
                c2 = b1_ * c2 + bgt * b2_;
                float h2n = b3_ * fmaxf(c2, 0.f);
                if (g == 0) h2b[wb][elem][u] = h2n;
            }
        } else {
            const int t2 = i + 2;
            if (t2 < TT) {
                // xw(t2) = b1 + x(t2) @ W1col  -> ring[t2&3]
                const float4* xr = (const float4*)(xrow + (size_t)t2 * FF);
                float a0 = 0.f, a1 = 0.f, a2 = 0.f, a3 = 0.f;
#pragma unroll
                for (int q = 0; q < FF / 4; ++q) {
                    float4 xx = xr[q];
                    a0 = fmaf(xx.x, w1r[4*q+0], a0);
                    a1 = fmaf(xx.y, w1r[4*q+1], a1);
                    a2 = fmaf(xx.z, w1r[4*q+2], a2);
                    a3 = fmaf(xx.w, w1r[4*q+3], a3);
                }
                ring[t2 & 3][elem][j] = bias + ((a0 + a1) + (a2 + a3));
            }
        }
        __syncthreads();
    }

    // dense head: final h2(255) written at iter 256 -> h2b[0]
    if (tid < EPB) {
        float acc = bd[0];
#pragma unroll
        for (int k = 0; k < HH; ++k) acc += h2b[0][tid][k] * Wd[k];
        out[b0 + tid] = acc;
    }
}

extern "C" void kernel_launch(void* const* d_in, const int* in_sizes, int n_in,
                              void* d_out, int out_size, void* d_ws, size_t ws_size,
                              hipStream_t stream) {
    const float* x  = (const float*)d_in[0];
    const float* W1 = (const float*)d_in[1];
    const float* U1 = (const float*)d_in[2];
    const float* b1 = (const float*)d_in[3];
    const float* W2 = (const float*)d_in[4];
    const float* U2 = (const float*)d_in[5];
    const float* b2 = (const float*)d_in[6];
    const float* Wd = (const float*)d_in[7];
    const float* bd = (const float*)d_in[8];
    float* out = (float*)d_out;
    const int B = in_sizes[0] / (TT * FF);   // 2048

    hipLaunchKernelGGL(lstm2_fused3, dim3(B / EPB), dim3(BLK), 0, stream,
                       x, W1, U1, b1, W2, U2, b2, Wd, bd, out, B);
}

// Round 7
// 1134.934 us; speedup vs baseline: 2.1162x; 2.1162x over previous
//
#include <hip/hip_runtime.h>
#include <math.h>

#define TT 256
#define FF 64
#define HH 20
#define G4 80    // 4*H
#define EPB 4    // batch elems per block
#define BLK 960  // 5 waves L1 | 5 waves L2 | 5 waves PROJ

__device__ __forceinline__ float sigmoidf_(float z) {
    return 1.0f / (1.0f + __expf(-z));
}

// quad_perm DPP: value from lane (lane ^ m) within each aligned quad (VALU, no DS)
__device__ __forceinline__ float qpx1(float v) {
    return __int_as_float(__builtin_amdgcn_mov_dpp(__float_as_int(v), 0xB1, 0xF, 0xF, true));
}
__device__ __forceinline__ float qpx2(float v) {
    return __int_as_float(__builtin_amdgcn_mov_dpp(__float_as_int(v), 0x4E, 0xF, 0xF, true));
}
__device__ __forceinline__ float qpx3(float v) {
    return __int_as_float(__builtin_amdgcn_mov_dpp(__float_as_int(v), 0x1B, 0xF, 0xF, true));
}

// ===== Fused: PROJ waves feed an LDS ring; L1/L2 producer-consumer; 1 barrier/step =====
// role 0 (tid<320):  layer-1 recurrence; thread=(elem, col via quad layout)
// role 1 (tid<640):  layer-2 recurrence, one step behind L1
// role 2 (tid<960):  xw(t+2) = b1 + x(t+2)@W1 into ring[(t+2)&3]; thread=(elem, col direct)
// Ring hazards: slot s written at iter s-2, read at iter s, rewritten at iter s+2
//   -> every pair separated by >=1 __syncthreads(). Prologue fills slots 0,1.
// launch_bounds min-waves=4 -> 128 VGPR cap: w1r[64]+working fits WITHOUT spill.
// (R6 post-mortem: min-waves=8 capped at 32 VGPR -> w1r spilled to scratch -> 7.4 GB fetch.)
__global__ __launch_bounds__(BLK, 4) void lstm2_fused3(
    const float* __restrict__ x,
    const float* __restrict__ W1, const float* __restrict__ U1, const float* __restrict__ b1,
    const float* __restrict__ W2, const float* __restrict__ U2, const float* __restrict__ b2,
    const float* __restrict__ Wd, const float* __restrict__ bd,
    float* __restrict__ out, int B)
{
    const int tid  = threadIdx.x;
    const int role = tid / 320;          // wave-uniform (320 = 5 waves)
    const int rt   = tid - role * 320;
    const int elem = rt / G4;            // 0..3
    const int j    = rt - elem * G4;     // 0..79
    const int g    = j & 3;              // gate: 0=i 1=f 2=c 3=o   (roles 0/1)
    const int u    = j >> 2;             // unit 0..19              (roles 0/1)
    const int col  = g * HH + u;         // weight column           (roles 0/1)
    const int b0   = blockIdx.x * EPB;

    __shared__ float h1b[2][EPB][24];
    __shared__ float h2b[2][EPB][24];
    __shared__ float ring[4][EPB][G4];   // xw ring, depth 4

    // ---- per-role weights ----
    float wA[HH], wB[HH];    // L1: U1 col | L2: W2 col, U2 col
    float w1r[FF];           // PROJ: W1 column
    float bias = 0.f;        // L2 b2 / PROJ b1
    const float* xrow = nullptr;

    if (role == 0) {
#pragma unroll
        for (int k = 0; k < HH; ++k) wA[k] = U1[k * G4 + col];
    } else if (role == 1) {
#pragma unroll
        for (int k = 0; k < HH; ++k) wA[k] = W2[k * G4 + col];
#pragma unroll
        for (int k = 0; k < HH; ++k) wB[k] = U2[k * G4 + col];
        bias = b2[col];
    } else {
#pragma unroll
        for (int f = 0; f < FF; ++f) w1r[f] = W1[f * G4 + j];
        bias = b1[j];
        xrow = x + (size_t)(b0 + elem) * TT * FF;
    }

    // zero h buffers
    for (int i = tid; i < 2 * EPB * 24; i += BLK) ((float*)h1b)[i] = 0.f;
    for (int i = tid; i < 2 * EPB * 24; i += BLK) ((float*)h2b)[i] = 0.f;

    // PROJ prologue: fill ring slots 0,1 (xw at t=0,1)
    if (role == 2) {
#pragma unroll
        for (int tp = 0; tp < 2; ++tp) {
            const float4* xr = (const float4*)(xrow + (size_t)tp * FF);
            float a0 = 0.f, a1 = 0.f, a2 = 0.f, a3 = 0.f;
#pragma unroll
            for (int q = 0; q < FF / 4; ++q) {
                float4 xx = xr[q];
                a0 = fmaf(xx.x, w1r[4*q+0], a0);
                a1 = fmaf(xx.y, w1r[4*q+1], a1);
                a2 = fmaf(xx.z, w1r[4*q+2], a2);
                a3 = fmaf(xx.w, w1r[4*q+3], a3);
            }
            ring[tp][elem][j] = bias + ((a0 + a1) + (a2 + a3));
        }
    }

    float c1 = 0.f, c2 = 0.f;
    __syncthreads();

    for (int i = 0; i <= TT; ++i) {
        const int rb = (i + 1) & 1;      // read h buffers
        const int wb = i & 1;            // write h buffers

        if (role == 0) {
            if (i < TT) {
                // z = xw(i) + h1(i-1) @ U1
                float xwc = ring[i & 3][elem][col];
                float zz0 = 0.f, zz1 = 0.f, zz2 = 0.f, zz3 = 0.f;
                const float4* hv = (const float4*)h1b[rb][elem];
#pragma unroll
                for (int q = 0; q < HH / 4; ++q) {
                    float4 hh = hv[q];
                    zz0 = fmaf(hh.x, wA[4*q+0], zz0);
                    zz1 = fmaf(hh.y, wA[4*q+1], zz1);
                    zz2 = fmaf(hh.z, wA[4*q+2], zz2);
                    zz3 = fmaf(hh.w, wA[4*q+3], zz3);
                }
                float z = xwc + ((zz0 + zz1) + (zz2 + zz3));

                float a = (g == 2) ? fmaxf(z, 0.f) : sigmoidf_(z);
                float a1 = qpx1(a), a2 = qpx2(a), a3 = qpx3(a);
                // valid in g==0 lanes: i=a, f=a1, c=a2, o=a3
                c1 = a1 * c1 + a * a2;
                float h1n = a3 * fmaxf(c1, 0.f);
                if (g == 0) h1b[wb][elem][u] = h1n;
            }
        } else if (role == 1) {
            if (i >= 1) {
                // z2 = b2 + h1(i-1) @ W2 + h2(i-2) @ U2
                float y0 = 0.f, y1 = 0.f, y2 = 0.f, y3 = 0.f;
                const float4* h1v = (const float4*)h1b[rb][elem];
                const float4* h2v = (const float4*)h2b[rb][elem];
#pragma unroll
                for (int q = 0; q < HH / 4; ++q) {
                    float4 ha = h1v[q];
                    float4 hb = h2v[q];
                    y0 = fmaf(ha.x, wA[4*q+0], y0);
                    y1 = fmaf(ha.y, wA[4*q+1], y1);
                    y2 = fmaf(ha.z, wA[4*q+2], y2);
                    y3 = fmaf(ha.w, wA[4*q+3], y3);
                    y0 = fmaf(hb.x, wB[4*q+0], y0);
                    y1 = fmaf(hb.y, wB[4*q+1], y1);
                    y2 = fmaf(hb.z, wB[4*q+2], y2);
                    y3 = fmaf(hb.w, wB[4*q+3], y3);
                }
                float z2v = bias + ((y0 + y1) + (y2 + y3));

                float bgt = (g == 2) ? fmaxf(z2v, 0.f) : sigmoidf_(z2v);
                float b1_ = qpx1(bgt), b2_ = qpx2(bgt), b3_ = qpx3(bgt);
                c2 = b1_ * c2 + bgt * b2_;
                float h2n = b3_ * fmaxf(c2, 0.f);
                if (g == 0) h2b[wb][elem][u] = h2n;
            }
        } else {
            const int t2 = i + 2;
            if (t2 < TT) {
                // xw(t2) = b1 + x(t2) @ W1col  -> ring[t2&3]
                const float4* xr = (const float4*)(xrow + (size_t)t2 * FF);
                float a0 = 0.f, a1 = 0.f, a2 = 0.f, a3 = 0.f;
#pragma unroll
                for (int q = 0; q < FF / 4; ++q) {
                    float4 xx = xr[q];
                    a0 = fmaf(xx.x, w1r[4*q+0], a0);
                    a1 = fmaf(xx.y, w1r[4*q+1], a1);
                    a2 = fmaf(xx.z, w1r[4*q+2], a2);
                    a3 = fmaf(xx.w, w1r[4*q+3], a3);
                }
                ring[t2 & 3][elem][j] = bias + ((a0 + a1) + (a2 + a3));
            }
        }
        __syncthreads();
    }

    // dense head: final h2(255) written at iter 256 -> h2b[0]
    if (tid < EPB) {
        float acc = bd[0];
#pragma unroll
        for (int k = 0; k < HH; ++k) acc += h2b[0][tid][k] * Wd[k];
        out[b0 + tid] = acc;
    }
}

extern "C" void kernel_launch(void* const* d_in, const int* in_sizes, int n_in,
                              void* d_out, int out_size, void* d_ws, size_t ws_size,
                              hipStream_t stream) {
    const float* x  = (const float*)d_in[0];
    const float* W1 = (const float*)d_in[1];
    const float* U1 = (const float*)d_in[2];
    const float* b1 = (const float*)d_in[3];
    const float* W2 = (const float*)d_in[4];
    const float* U2 = (const float*)d_in[5];
    const float* b2 = (const float*)d_in[6];
    const float* Wd = (const float*)d_in[7];
    const float* bd = (const float*)d_in[8];
    float* out = (float*)d_out;
    const int B = in_sizes[0] / (TT * FF);   // 2048

    hipLaunchKernelGGL(lstm2_fused3, dim3(B / EPB), dim3(BLK), 0, stream,
                       x, W1, U1, b1, W2, U2, b2, Wd, bd, out, B);
}

// Round 8
// 865.653 us; speedup vs baseline: 2.7745x; 1.3111x over previous
//
#include <hip/hip_runtime.h>
#include <math.h>

#define TT 256
#define FF 64
#define HH 20
#define G4 80   // 4*H
#define EPB 4   // batch elems per block
#define PBLK 320
#define RBLK 640  // 5 waves L1 + 5 waves L2
#define TC 64
#define BLOB_BYTES 19456  // 15*80 float4 = 19200, padded to 256

__device__ __forceinline__ float sigmoidf_(float z) {
    // v_exp + v_rcp (approx rcp: ~1ulp, fine vs 1e-2 threshold)
    return __builtin_amdgcn_rcpf(1.0f + __expf(-z));
}

// quad_perm DPP: value from lane (lane ^ m) within each aligned quad (VALU, no DS)
__device__ __forceinline__ float qpx1(float v) {
    return __int_as_float(__builtin_amdgcn_mov_dpp(__float_as_int(v), 0xB1, 0xF, 0xF, true));
}
__device__ __forceinline__ float qpx2(float v) {
    return __int_as_float(__builtin_amdgcn_mov_dpp(__float_as_int(v), 0x4E, 0xF, 0xF, true));
}
__device__ __forceinline__ float qpx3(float v) {
    return __int_as_float(__builtin_amdgcn_mov_dpp(__float_as_int(v), 0x1B, 0xF, 0xF, true));
}

// ===== K0: repack U1,W2,U2 into k-interleaved blob: blob4[(m*5+kq)*80+col] =
//           float4{ M[(kq*4+j)*80+col] j=0..3 }.  19.2 KB, L1$-resident.
// Rec threads then load weights as 5/10 coalesced dwordx4 from ONE base (cheap reload).
__global__ void wprep(const float* __restrict__ U1, const float* __restrict__ W2,
                      const float* __restrict__ U2, float4* __restrict__ blob) {
    int i = threadIdx.x + blockIdx.x * blockDim.x;
    if (i >= 15 * G4) return;
    int q = i / G4, col = i - q * G4;
    int m = q / 5, kq = q - m * 5;
    const float* M = (m == 0) ? U1 : (m == 1) ? W2 : U2;
    float4 v;
    v.x = M[(kq * 4 + 0) * G4 + col];
    v.y = M[(kq * 4 + 1) * G4 + col];
    v.z = M[(kq * 4 + 2) * G4 + col];
    v.w = M[(kq * 4 + 3) * G4 + col];
    blob[i] = v;
}

// ===== K1: xw[t][b][col] = b1[col] + sum_f x[b][t][f]*W1[f][col] =====
__global__ __launch_bounds__(PBLK, 2) void proj_x(
    const float* __restrict__ x, const float* __restrict__ W1,
    const float* __restrict__ b1, float* __restrict__ xw, int B)
{
    __shared__ float xs[TC][FF + 4];
    __shared__ float ws[FF][G4];
    __shared__ float bs[G4];
    const int tid = threadIdx.x;
    const int b   = blockIdx.x >> 2;
    const int t0  = (blockIdx.x & 3) * TC;

    const float4* xg = (const float4*)(x + ((size_t)b * TT + t0) * FF);
    for (int i = tid; i < TC * FF / 4; i += PBLK) {
        int t = i >> 4, q = i & 15;
        *(float4*)&xs[t][q * 4] = xg[i];
    }
    const float4* wg = (const float4*)W1;
    float4* wsv = (float4*)ws;
    for (int i = tid; i < FF * G4 / 4; i += PBLK) wsv[i] = wg[i];
    if (tid < G4) bs[tid] = b1[tid];
    __syncthreads();

    const int colq = tid % 20;
    const int tq   = tid / 20;
    const int c0   = colq * 4;
    const int tb   = tq * 4;

    const float4 bias4 = *(const float4*)&bs[c0];
    float4 acc[4];
#pragma unroll
    for (int i = 0; i < 4; ++i) acc[i] = bias4;

#pragma unroll 16
    for (int f = 0; f < FF; ++f) {
        float4 wv = *(const float4*)&ws[f][c0];
        float x0 = xs[tb + 0][f], x1 = xs[tb + 1][f];
        float x2 = xs[tb + 2][f], x3 = xs[tb + 3][f];
        acc[0].x = fmaf(x0, wv.x, acc[0].x); acc[0].y = fmaf(x0, wv.y, acc[0].y);
        acc[0].z = fmaf(x0, wv.z, acc[0].z); acc[0].w = fmaf(x0, wv.w, acc[0].w);
        acc[1].x = fmaf(x1, wv.x, acc[1].x); acc[1].y = fmaf(x1, wv.y, acc[1].y);
        acc[1].z = fmaf(x1, wv.z, acc[1].z); acc[1].w = fmaf(x1, wv.w, acc[1].w);
        acc[2].x = fmaf(x2, wv.x, acc[2].x); acc[2].y = fmaf(x2, wv.y, acc[2].y);
        acc[2].z = fmaf(x2, wv.z, acc[2].z); acc[2].w = fmaf(x2, wv.w, acc[2].w);
        acc[3].x = fmaf(x3, wv.x, acc[3].x); acc[3].y = fmaf(x3, wv.y, acc[3].y);
        acc[3].z = fmaf(x3, wv.z, acc[3].z); acc[3].w = fmaf(x3, wv.w, acc[3].w);
    }
#pragma unroll
    for (int i = 0; i < 4; ++i) {
        *(float4*)&xw[((size_t)(t0 + tb + i) * B + b) * G4 + c0] = acc[i];
    }
}

// ============ K2: producer-consumer recurrence, 1 barrier/step, blob weights ============
__global__ __launch_bounds__(RBLK, 2) void lstm2_pc(
    const float* __restrict__ xw, const float4* __restrict__ blob,
    const float* __restrict__ b2,
    const float* __restrict__ Wd, const float* __restrict__ bd,
    float* __restrict__ out, int B)
{
    const int tid  = threadIdx.x;
    const bool isL1 = tid < 320;
    const int rt   = isL1 ? tid : tid - 320;
    const int elem = rt / G4;          // 0..3
    const int j    = rt - elem * G4;   // 0..79
    const int g    = j & 3;            // gate: 0=i 1=f 2=c 3=o
    const int u    = j >> 2;           // unit 0..19
    const int col  = g * HH + u;
    const int b0   = blockIdx.x * EPB;

    __shared__ float h1b[2][EPB][24];
    __shared__ float h2b[2][EPB][24];

    // per-thread weight bases into the blob (loop-invariant; reloads are
    // single coalesced dwordx4 from L1$ — designed-for-reload, not residency)
    const float4* wpA = blob + col;            // L1: U1 rows (q=0..4)
    const float4* wpB = blob + 5 * G4 + col;   // L2: W2 rows (q=0..4)
    const float4* wpC = blob + 10 * G4 + col;  // L2: U2 rows (q=0..4)
    const float bias = isL1 ? 0.f : b2[col];

    for (int i = tid; i < 2 * EPB * 24; i += RBLK) ((float*)h1b)[i] = 0.f;
    for (int i = tid; i < 2 * EPB * 24; i += RBLK) ((float*)h2b)[i] = 0.f;

    const size_t tstride = (size_t)B * G4;
    const float* xwp = xw + (size_t)(b0 + elem) * G4 + col;   // t=0 position
    float xwc = isL1 ? xwp[0] : 0.f;
    xwp += tstride;                    // points at t=1
    float c1 = 0.f, c2 = 0.f;
    __syncthreads();

    for (int i = 0; i <= TT; ++i) {
        const int rb = (i + 1) & 1;    // read buffers (prev iter's writes / zeros)
        const int wb = i & 1;          // write buffers

        if (isL1 && i < TT) {
            // prefetch xw(i+1)
            float xwn = 0.f;
            if (i + 1 < TT) xwn = *xwp;
            xwp += tstride;

            // z = xw(i) + h1(i-1) @ U1
            float zz0 = 0.f, zz1 = 0.f, zz2 = 0.f, zz3 = 0.f;
            const float4* hv = (const float4*)h1b[rb][elem];
#pragma unroll
            for (int q = 0; q < HH / 4; ++q) {
                float4 w = wpA[q * G4];
                float4 hh = hv[q];
                zz0 = fmaf(hh.x, w.x, zz0);
                zz1 = fmaf(hh.y, w.y, zz1);
                zz2 = fmaf(hh.z, w.z, zz2);
                zz3 = fmaf(hh.w, w.w, zz3);
            }
            float z = xwc + ((zz0 + zz1) + (zz2 + zz3));

            float a = (g == 2) ? fmaxf(z, 0.f) : sigmoidf_(z);
            float a1 = qpx1(a), a2 = qpx2(a), a3 = qpx3(a);
            // valid in g==0 lanes: i=a, f=a1, c=a2, o=a3
            c1 = a1 * c1 + a * a2;
            float h1n = a3 * fmaxf(c1, 0.f);
            if (g == 0) h1b[wb][elem][u] = h1n;
            xwc = xwn;
        }
        if (!isL1 && i >= 1) {
            // z2 = b2 + h1(i-1) @ W2 + h2(i-2) @ U2
            float y0 = 0.f, y1 = 0.f, y2 = 0.f, y3 = 0.f;
            const float4* h1v = (const float4*)h1b[rb][elem];
            const float4* h2v = (const float4*)h2b[rb][elem];
#pragma unroll
            for (int q = 0; q < HH / 4; ++q) {
                float4 wa = wpB[q * G4];
                float4 wb_ = wpC[q * G4];
                float4 ha = h1v[q];
                float4 hb = h2v[q];
                y0 = fmaf(ha.x, wa.x, y0);
                y1 = fmaf(ha.y, wa.y, y1);
                y2 = fmaf(ha.z, wa.z, y2);
                y3 = fmaf(ha.w, wa.w, y3);
                y0 = fmaf(hb.x, wb_.x, y0);
                y1 = fmaf(hb.y, wb_.y, y1);
                y2 = fmaf(hb.z, wb_.z, y2);
                y3 = fmaf(hb.w, wb_.w, y3);
            }
            float z2v = bias + ((y0 + y1) + (y2 + y3));

            float bgt = (g == 2) ? fmaxf(z2v, 0.f) : sigmoidf_(z2v);
            float b1_ = qpx1(bgt), b2_ = qpx2(bgt), b3_ = qpx3(bgt);
            c2 = b1_ * c2 + bgt * b2_;
            float h2n = b3_ * fmaxf(c2, 0.f);
            if (g == 0) h2b[wb][elem][u] = h2n;
        }
        __syncthreads();
    }

    // final h2(255) written at iter 256 -> h2b[0]
    if (tid < EPB) {
        float acc = bd[0];
#pragma unroll
        for (int k = 0; k < HH; ++k) acc += h2b[0][tid][k] * Wd[k];
        out[b0 + tid] = acc;
    }
}

// ================= Fallback (ws too small): fused single kernel =================
__global__ __launch_bounds__(PBLK, 2) void lstm2_fused_fb(
    const float* __restrict__ x,
    const float* __restrict__ W1, const float* __restrict__ U1, const float* __restrict__ b1,
    const float* __restrict__ W2, const float* __restrict__ U2, const float* __restrict__ b2,
    const float* __restrict__ Wd, const float* __restrict__ bd,
    float* __restrict__ out)
{
    const int tid  = threadIdx.x;
    const int elem = tid / G4;
    const int j    = tid - elem * G4;
    const int g    = j & 3;
    const int u    = j >> 2;
    const int col  = g * HH + u;
    const int b0   = blockIdx.x * EPB;

    __shared__ float xs[2][EPB][FF];
    __shared__ float h1b[2][EPB][24];
    __shared__ float h2b[2][EPB][24];

    float w1[FF], u1[HH], w2[HH], u2[HH];
#pragma unroll
    for (int f = 0; f < FF; ++f) w1[f] = W1[f * G4 + col];
#pragma unroll
    for (int k = 0; k < HH; ++k) u1[k] = U1[k * G4 + col];
#pragma unroll
    for (int k = 0; k < HH; ++k) w2[k] = W2[k * G4 + col];
#pragma unroll
    for (int k = 0; k < HH; ++k) u2[k] = U2[k * G4 + col];
    const float bias1 = b1[col];
    const float bias2 = b2[col];

    for (int i = tid; i < 2 * EPB * 24; i += PBLK) ((float*)h1b)[i] = 0.f;
    for (int i = tid; i < 2 * EPB * 24; i += PBLK) ((float*)h2b)[i] = 0.f;
    if (tid < EPB * FF) {
        int e2 = tid >> 6, f2 = tid & 63;
        xs[0][e2][f2] = x[((long)(b0 + e2) * TT + 0) * FF + f2];
    }
    __syncthreads();

    float c1 = 0.f, c2 = 0.f;
    for (int t = 0; t < TT; ++t) {
        const int cur = t & 1;
        float xpre = 0.f;
        if (t + 1 < TT && tid < EPB * FF) {
            int e2 = tid >> 6, f2 = tid & 63;
            xpre = x[((long)(b0 + e2) * TT + (t + 1)) * FF + f2];
        }
        float zz0 = 0.f, zz1 = 0.f, zz2 = 0.f, zz3 = 0.f;
        const float4* xv = (const float4*)xs[cur][elem];
#pragma unroll
        for (int q = 0; q < FF / 4; ++q) {
            float4 xx = xv[q];
            zz0 = fmaf(xx.x, w1[4*q+0], zz0);
            zz1 = fmaf(xx.y, w1[4*q+1], zz1);
            zz2 = fmaf(xx.z, w1[4*q+2], zz2);
            zz3 = fmaf(xx.w, w1[4*q+3], zz3);
        }
        const float4* hv = (const float4*)h1b[cur][elem];
#pragma unroll
        for (int q = 0; q < HH / 4; ++q) {
            float4 hh = hv[q];
            zz0 = fmaf(hh.x, u1[4*q+0], zz0);
            zz1 = fmaf(hh.y, u1[4*q+1], zz1);
            zz2 = fmaf(hh.z, u1[4*q+2], zz2);
            zz3 = fmaf(hh.w, u1[4*q+3], zz3);
        }
        float z = bias1 + ((zz0 + zz1) + (zz2 + zz3));
        float a = (g == 2) ? fmaxf(z, 0.f) : sigmoidf_(z);
        float a1 = qpx1(a), a2 = qpx2(a), a3 = qpx3(a);
        c1 = a1 * c1 + a * a2;
        float h1n = a3 * fmaxf(c1, 0.f);
        if (g == 0) h1b[cur ^ 1][elem][u] = h1n;
        __syncthreads();
        if (t + 1 < TT && tid < EPB * FF) xs[cur ^ 1][tid >> 6][tid & 63] = xpre;

        float y0 = 0.f, y1 = 0.f, y2 = 0.f, y3 = 0.f;
        const float4* h1v = (const float4*)h1b[cur ^ 1][elem];
        const float4* h2v = (const float4*)h2b[cur][elem];
#pragma unroll
        for (int q = 0; q < HH / 4; ++q) {
            float4 ha = h1v[q];
            float4 hb = h2v[q];
            y0 = fmaf(ha.x, w2[4*q+0], y0);
            y1 = fmaf(ha.y, w2[4*q+1], y1);
            y2 = fmaf(ha.z, w2[4*q+2], y2);
            y3 = fmaf(ha.w, w2[4*q+3], y3);
            y0 = fmaf(hb.x, u2[4*q+0], y0);
            y1 = fmaf(hb.y, u2[4*q+1], y1);
            y2 = fmaf(hb.z, u2[4*q+2], y2);
            y3 = fmaf(hb.w, u2[4*q+3], y3);
        }
        float z2v = bias2 + ((y0 + y1) + (y2 + y3));
        float bgt = (g == 2) ? fmaxf(z2v, 0.f) : sigmoidf_(z2v);
        float b1_ = qpx1(bgt), b2_ = qpx2(bgt), b3_ = qpx3(bgt);
        c2 = b1_ * c2 + bgt * b2_;
        float h2n = b3_ * fmaxf(c2, 0.f);
        if (g == 0) h2b[cur ^ 1][elem][u] = h2n;
        __syncthreads();
    }
    if (j == 0) {
        float acc = bd[0];
#pragma unroll
        for (int k = 0; k < HH; ++k) acc += h2b[0][elem][k] * Wd[k];
        out[b0 + elem] = acc;
    }
}

extern "C" void kernel_launch(void* const* d_in, const int* in_sizes, int n_in,
                              void* d_out, int out_size, void* d_ws, size_t ws_size,
                              hipStream_t stream) {
    const float* x  = (const float*)d_in[0];
    const float* W1 = (const float*)d_in[1];
    const float* U1 = (const float*)d_in[2];
    const float* b1 = (const float*)d_in[3];
    const float* W2 = (const float*)d_in[4];
    const float* U2 = (const float*)d_in[5];
    const float* b2 = (const float*)d_in[6];
    const float* Wd = (const float*)d_in[7];
    const float* bd = (const float*)d_in[8];
    float* out = (float*)d_out;
    const int B = in_sizes[0] / (TT * FF);   // 2048

    const size_t need = (size_t)BLOB_BYTES + (size_t)B * TT * G4 * sizeof(float);
    if (ws_size >= need) {
        float4* blob = (float4*)d_ws;
        float*  xw   = (float*)((char*)d_ws + BLOB_BYTES);
        hipLaunchKernelGGL(wprep, dim3(5), dim3(256), 0, stream, U1, W2, U2, blob);
        hipLaunchKernelGGL(proj_x, dim3(B * (TT / TC)), dim3(PBLK), 0, stream,
                           x, W1, b1, xw, B);
        hipLaunchKernelGGL(lstm2_pc, dim3(B / EPB), dim3(RBLK), 0, stream,
                           xw, blob, b2, Wd, bd, out, B);
    } else {
        hipLaunchKernelGGL(lstm2_fused_fb, dim3(B / EPB), dim3(PBLK), 0, stream,
                           x, W1, U1, b1, W2, U2, b2, Wd, bd, out);
    }
}

// Round 9
// 294.385 us; speedup vs baseline: 8.1586x; 2.9405x over previous
//
#include <hip/hip_runtime.h>
#include <math.h>

#define TT 256
#define FF 64
#define HH 20
#define G4 80   // 4*H
#define EPB 4   // batch elems per block (rec)
#define PBLK 320
#define RBLK 640  // 5 waves L1 + 5 waves L2
#define TC 128    // t-chunk per proj block
#define BLOB_BYTES 19456  // 15*80 float4 = 19200, padded

__device__ __forceinline__ float sigmoidf_(float z) {
    return __builtin_amdgcn_rcpf(1.0f + __expf(-z));
}

// quad_perm DPP: value from lane (lane ^ m) within each aligned quad (VALU, no DS)
__device__ __forceinline__ float qpx1(float v) {
    return __int_as_float(__builtin_amdgcn_mov_dpp(__float_as_int(v), 0xB1, 0xF, 0xF, true));
}
__device__ __forceinline__ float qpx2(float v) {
    return __int_as_float(__builtin_amdgcn_mov_dpp(__float_as_int(v), 0x4E, 0xF, 0xF, true));
}
__device__ __forceinline__ float qpx3(float v) {
    return __int_as_float(__builtin_amdgcn_mov_dpp(__float_as_int(v), 0x1B, 0xF, 0xF, true));
}

// ===== K0: lane-ordered blob: blob4[q*80 + j] = {M[(kq*4+k)*80 + col(j)]}
// col(j) = (j&3)*20 + (j>>2) — the rec kernel's lane->col mapping BAKED IN,
// so rec's weight loads are lane-contiguous (stride 16B) off one base.
__global__ void wprep(const float* __restrict__ U1, const float* __restrict__ W2,
                      const float* __restrict__ U2, float4* __restrict__ blob) {
    int i = threadIdx.x + blockIdx.x * blockDim.x;
    if (i >= 15 * G4) return;
    int q = i / G4, j = i - q * G4;
    int m = q / 5, kq = q - m * 5;
    int col = (j & 3) * HH + (j >> 2);
    const float* M = (m == 0) ? U1 : (m == 1) ? W2 : U2;
    float4 v;
    v.x = M[(kq * 4 + 0) * G4 + col];
    v.y = M[(kq * 4 + 1) * G4 + col];
    v.z = M[(kq * 4 + 2) * G4 + col];
    v.w = M[(kq * 4 + 3) * G4 + col];
    blob[i] = v;
}

// ===== K1: xw[t][b][col] = b1[col] + sum_f x[b][t][f]*W1[f][col]; TC=128, 8-row tiles =====
__global__ __launch_bounds__(PBLK, 2) void proj_x(
    const float* __restrict__ x, const float* __restrict__ W1,
    const float* __restrict__ b1, float* __restrict__ xw, int B)
{
    __shared__ float xs[TC][FF + 4];   // 34.8 KB
    __shared__ float ws[FF][G4];       // 20 KB
    __shared__ float bs[G4];
    const int tid = threadIdx.x;
    const int b   = blockIdx.x >> 1;
    const int t0  = (blockIdx.x & 1) * TC;

    const float4* xg = (const float4*)(x + ((size_t)b * TT + t0) * FF);
    for (int i = tid; i < TC * FF / 4; i += PBLK) {
        int t = i >> 4, q = i & 15;
        *(float4*)&xs[t][q * 4] = xg[i];
    }
    const float4* wg = (const float4*)W1;
    float4* wsv = (float4*)ws;
    for (int i = tid; i < FF * G4 / 4; i += PBLK) wsv[i] = wg[i];
    if (tid < G4) bs[tid] = b1[tid];
    __syncthreads();

    const int colq = tid % 20;
    const int tq   = tid / 20;    // 0..15
    const int c0   = colq * 4;
    const int tb   = tq * 8;      // 8 rows per thread

    const float4 bias4 = *(const float4*)&bs[c0];
    float4 acc[8];
#pragma unroll
    for (int i = 0; i < 8; ++i) acc[i] = bias4;

#pragma unroll 8
    for (int f = 0; f < FF; ++f) {
        float4 wv = *(const float4*)&ws[f][c0];
#pragma unroll
        for (int r = 0; r < 8; ++r) {
            float xr = xs[tb + r][f];
            acc[r].x = fmaf(xr, wv.x, acc[r].x);
            acc[r].y = fmaf(xr, wv.y, acc[r].y);
            acc[r].z = fmaf(xr, wv.z, acc[r].z);
            acc[r].w = fmaf(xr, wv.w, acc[r].w);
        }
    }
#pragma unroll
    for (int i = 0; i < 8; ++i) {
        *(float4*)&xw[((size_t)(t0 + tb + i) * B + b) * G4 + c0] = acc[i];
    }
}

// ============ K2: producer-consumer recurrence (R5 structure), blob-sourced weights ============
__global__ __launch_bounds__(RBLK, 2) void lstm2_pc(
    const float* __restrict__ xw, const float4* __restrict__ blob,
    const float* __restrict__ b2,
    const float* __restrict__ Wd, const float* __restrict__ bd,
    float* __restrict__ out, int B)
{
    const int tid  = threadIdx.x;
    const bool isL1 = tid < 320;
    const int rt   = isL1 ? tid : tid - 320;
    const int elem = rt / G4;          // 0..3
    const int j    = rt - elem * G4;   // 0..79
    const int g    = j & 3;            // gate: 0=i 1=f 2=c 3=o
    const int u    = j >> 2;           // unit 0..19
    const int col  = g * HH + u;
    const int b0   = blockIdx.x * EPB;

    __shared__ float h1b[2][EPB][24];
    __shared__ float h2b[2][EPB][24];

    // R5-style pre-loop arrays; source = lane-ordered blob (coalesced dwordx4,
    // one base + imm offsets). Compiler may remat per-step — remat is now cheap.
    const float4* wb4 = blob + j;
    float wA[HH], wB[HH];
    if (isL1) {
#pragma unroll
        for (int q = 0; q < 5; ++q) {
            float4 v = wb4[q * G4];
            wA[4*q+0] = v.x; wA[4*q+1] = v.y; wA[4*q+2] = v.z; wA[4*q+3] = v.w;
        }
    } else {
#pragma unroll
        for (int q = 0; q < 5; ++q) {
            float4 v = wb4[(5 + q) * G4];
            wA[4*q+0] = v.x; wA[4*q+1] = v.y; wA[4*q+2] = v.z; wA[4*q+3] = v.w;
            float4 v2 = wb4[(10 + q) * G4];
            wB[4*q+0] = v2.x; wB[4*q+1] = v2.y; wB[4*q+2] = v2.z; wB[4*q+3] = v2.w;
        }
    }
    const float bias = isL1 ? 0.f : b2[col];

    for (int i = tid; i < 2 * EPB * 24; i += RBLK) ((float*)h1b)[i] = 0.f;
    for (int i = tid; i < 2 * EPB * 24; i += RBLK) ((float*)h2b)[i] = 0.f;

    const size_t tstride = (size_t)B * G4;
    const float* xwp = xw + (size_t)(b0 + elem) * G4 + col;
    float xwc = isL1 ? xwp[0] : 0.f;
    xwp += tstride;
    float c1 = 0.f, c2 = 0.f;
    __syncthreads();

    for (int i = 0; i <= TT; ++i) {
        const int rb = (i + 1) & 1;    // read buffers
        const int wb = i & 1;          // write buffers

        if (isL1 && i < TT) {
            float xwn = 0.f;
            if (i + 1 < TT) xwn = *xwp;
            xwp += tstride;

            // z = xw(i) + h1(i-1) @ U1
            float zz0 = 0.f, zz1 = 0.f, zz2 = 0.f, zz3 = 0.f;
            const float4* hv = (const float4*)h1b[rb][elem];
#pragma unroll
            for (int q = 0; q < HH / 4; ++q) {
                float4 hh = hv[q];
                zz0 = fmaf(hh.x, wA[4*q+0], zz0);
                zz1 = fmaf(hh.y, wA[4*q+1], zz1);
                zz2 = fmaf(hh.z, wA[4*q+2], zz2);
                zz3 = fmaf(hh.w, wA[4*q+3], zz3);
            }
            float z = xwc + ((zz0 + zz1) + (zz2 + zz3));

            float a = (g == 2) ? fmaxf(z, 0.f) : sigmoidf_(z);
            float a1 = qpx1(a), a2 = qpx2(a), a3 = qpx3(a);
            c1 = a1 * c1 + a * a2;
            float h1n = a3 * fmaxf(c1, 0.f);
            if (g == 0) h1b[wb][elem][u] = h1n;
            xwc = xwn;
        }
        if (!isL1 && i >= 1) {
            // z2 = b2 + h1(i-1) @ W2 + h2(i-2) @ U2
            float y0 = 0.f, y1 = 0.f, y2 = 0.f, y3 = 0.f;
            const float4* h1v = (const float4*)h1b[rb][elem];
            const float4* h2v = (const float4*)h2b[rb][elem];
#pragma unroll
            for (int q = 0; q < HH / 4; ++q) {
                float4 ha = h1v[q];
                float4 hb = h2v[q];
                y0 = fmaf(ha.x, wA[4*q+0], y0);
                y1 = fmaf(ha.y, wA[4*q+1], y1);
                y2 = fmaf(ha.z, wA[4*q+2], y2);
                y3 = fmaf(ha.w, wA[4*q+3], y3);
                y0 = fmaf(hb.x, wB[4*q+0], y0);
                y1 = fmaf(hb.y, wB[4*q+1], y1);
                y2 = fmaf(hb.z, wB[4*q+2], y2);
                y3 = fmaf(hb.w, wB[4*q+3], y3);
            }
            float z2v = bias + ((y0 + y1) + (y2 + y3));

            float bgt = (g == 2) ? fmaxf(z2v, 0.f) : sigmoidf_(z2v);
            float b1_ = qpx1(bgt), b2_ = qpx2(bgt), b3_ = qpx3(bgt);
            c2 = b1_ * c2 + bgt * b2_;
            float h2n = b3_ * fmaxf(c2, 0.f);
            if (g == 0) h2b[wb][elem][u] = h2n;
        }
        __syncthreads();
    }

    if (tid < EPB) {
        float acc = bd[0];
#pragma unroll
        for (int k = 0; k < HH; ++k) acc += h2b[0][tid][k] * Wd[k];
        out[b0 + tid] = acc;
    }
}

// ================= Fallback (ws too small): fused single kernel =================
__global__ __launch_bounds__(PBLK, 2) void lstm2_fused_fb(
    const float* __restrict__ x,
    const float* __restrict__ W1, const float* __restrict__ U1, const float* __restrict__ b1,
    const float* __restrict__ W2, const float* __restrict__ U2, const float* __restrict__ b2,
    const float* __restrict__ Wd, const float* __restrict__ bd,
    float* __restrict__ out)
{
    const int tid  = threadIdx.x;
    const int elem = tid / G4;
    const int j    = tid - elem * G4;
    const int g    = j & 3;
    const int u    = j >> 2;
    const int col  = g * HH + u;
    const int b0   = blockIdx.x * EPB;

    __shared__ float xs[2][EPB][FF];
    __shared__ float h1b[2][EPB][24];
    __shared__ float h2b[2][EPB][24];

    float w1[FF], u1[HH], w2[HH], u2[HH];
#pragma unroll
    for (int f = 0; f < FF; ++f) w1[f] = W1[f * G4 + col];
#pragma unroll
    for (int k = 0; k < HH; ++k) u1[k] = U1[k * G4 + col];
#pragma unroll
    for (int k = 0; k < HH; ++k) w2[k] = W2[k * G4 + col];
#pragma unroll
    for (int k = 0; k < HH; ++k) u2[k] = U2[k * G4 + col];
    const float bias1 = b1[col];
    const float bias2 = b2[col];

    for (int i = tid; i < 2 * EPB * 24; i += PBLK) ((float*)h1b)[i] = 0.f;
    for (int i = tid; i < 2 * EPB * 24; i += PBLK) ((float*)h2b)[i] = 0.f;
    if (tid < EPB * FF) {
        int e2 = tid >> 6, f2 = tid & 63;
        xs[0][e2][f2] = x[((long)(b0 + e2) * TT + 0) * FF + f2];
    }
    __syncthreads();

    float c1 = 0.f, c2 = 0.f;
    for (int t = 0; t < TT; ++t) {
        const int cur = t & 1;
        float xpre = 0.f;
        if (t + 1 < TT && tid < EPB * FF) {
            int e2 = tid >> 6, f2 = tid & 63;
            xpre = x[((long)(b0 + e2) * TT + (t + 1)) * FF + f2];
        }
        float zz0 = 0.f, zz1 = 0.f, zz2 = 0.f, zz3 = 0.f;
        const float4* xv = (const float4*)xs[cur][elem];
#pragma unroll
        for (int q = 0; q < FF / 4; ++q) {
            float4 xx = xv[q];
            zz0 = fmaf(xx.x, w1[4*q+0], zz0);
            zz1 = fmaf(xx.y, w1[4*q+1], zz1);
            zz2 = fmaf(xx.z, w1[4*q+2], zz2);
            zz3 = fmaf(xx.w, w1[4*q+3], zz3);
        }
        const float4* hv = (const float4*)h1b[cur][elem];
#pragma unroll
        for (int q = 0; q < HH / 4; ++q) {
            float4 hh = hv[q];
            zz0 = fmaf(hh.x, u1[4*q+0], zz0);
            zz1 = fmaf(hh.y, u1[4*q+1], zz1);
            zz2 = fmaf(hh.z, u1[4*q+2], zz2);
            zz3 = fmaf(hh.w, u1[4*q+3], zz3);
        }
        float z = bias1 + ((zz0 + zz1) + (zz2 + zz3));
        float a = (g == 2) ? fmaxf(z, 0.f) : sigmoidf_(z);
        float a1 = qpx1(a), a2 = qpx2(a), a3 = qpx3(a);
        c1 = a1 * c1 + a * a2;
        float h1n = a3 * fmaxf(c1, 0.f);
        if (g == 0) h1b[cur ^ 1][elem][u] = h1n;
        __syncthreads();
        if (t + 1 < TT && tid < EPB * FF) xs[cur ^ 1][tid >> 6][tid & 63] = xpre;

        float y0 = 0.f, y1 = 0.f, y2 = 0.f, y3 = 0.f;
        const float4* h1v = (const float4*)h1b[cur ^ 1][elem];
        const float4* h2v = (const float4*)h2b[cur][elem];
#pragma unroll
        for (int q = 0; q < HH / 4; ++q) {
            float4 ha = h1v[q];
            float4 hb = h2v[q];
            y0 = fmaf(ha.x, w2[4*q+0], y0);
            y1 = fmaf(ha.y, w2[4*q+1], y1);
            y2 = fmaf(ha.z, w2[4*q+2], y2);
            y3 = fmaf(ha.w, w2[4*q+3], y3);
            y0 = fmaf(hb.x, u2[4*q+0], y0);
            y1 = fmaf(hb.y, u2[4*q+1], y1);
            y2 = fmaf(hb.z, u2[4*q+2], y2);
            y3 = fmaf(hb.w, u2[4*q+3], y3);
        }
        float z2v = bias2 + ((y0 + y1) + (y2 + y3));
        float bgt = (g == 2) ? fmaxf(z2v, 0.f) : sigmoidf_(z2v);
        float b1_ = qpx1(bgt), b2_ = qpx2(bgt), b3_ = qpx3(bgt);
        c2 = b1_ * c2 + bgt * b2_;
        float h2n = b3_ * fmaxf(c2, 0.f);
        if (g == 0) h2b[cur ^ 1][elem][u] = h2n;
        __syncthreads();
    }
    if (j == 0) {
        float acc = bd[0];
#pragma unroll
        for (int k = 0; k < HH; ++k) acc += h2b[0][elem][k] * Wd[k];
        out[b0 + elem] = acc;
    }
}

extern "C" void kernel_launch(void* const* d_in, const int* in_sizes, int n_in,
                              void* d_out, int out_size, void* d_ws, size_t ws_size,
                              hipStream_t stream) {
    const float* x  = (const float*)d_in[0];
    const float* W1 = (const float*)d_in[1];
    const float* U1 = (const float*)d_in[2];
    const float* b1 = (const float*)d_in[3];
    const float* W2 = (const float*)d_in[4];
    const float* U2 = (const float*)d_in[5];
    const float* b2 = (const float*)d_in[6];
    const float* Wd = (const float*)d_in[7];
    const float* bd = (const float*)d_in[8];
    float* out = (float*)d_out;
    const int B = in_sizes[0] / (TT * FF);   // 2048

    const size_t need = (size_t)BLOB_BYTES + (size_t)B * TT * G4 * sizeof(float);
    if (ws_size >= need) {
        float4* blob = (float4*)d_ws;
        float*  xw   = (float*)((char*)d_ws + BLOB_BYTES);
        hipLaunchKernelGGL(wprep, dim3(5), dim3(256), 0, stream, U1, W2, U2, blob);
        hipLaunchKernelGGL(proj_x, dim3(B * (TT / TC)), dim3(PBLK), 0, stream,
                           x, W1, b1, xw, B);
        hipLaunchKernelGGL(lstm2_pc, dim3(B / EPB), dim3(RBLK), 0, stream,
                           xw, blob, b2, Wd, bd, out, B);
    } else {
        hipLaunchKernelGGL(lstm2_fused_fb, dim3(B / EPB), dim3(PBLK), 0, stream,
                           x, W1, U1, b1, W2, U2, b2, Wd, bd, out);
    }
}

// Round 10
// 293.577 us; speedup vs baseline: 8.1811x; 1.0028x over previous
//
#include <hip/hip_runtime.h>
#include <math.h>

#define TT 256
#define FF 64
#define HH 20
#define G4 80   // 4*H
#define EPB 4   // batch elems per block (rec)
#define PBLK 320
#define RBLK 640  // 5 waves L1 + 5 waves L2
#define TC 128    // t-chunk per proj block
#define BLOB_BYTES 19456  // 15*80 float4 = 19200, padded

__device__ __forceinline__ float sigmoidf_(float z) {
    return __builtin_amdgcn_rcpf(1.0f + __expf(-z));
}

// quad_perm DPP: value from lane (lane ^ m) within each aligned quad (VALU, no DS)
__device__ __forceinline__ float qpx1(float v) {
    return __int_as_float(__builtin_amdgcn_mov_dpp(__float_as_int(v), 0xB1, 0xF, 0xF, true));
}
__device__ __forceinline__ float qpx2(float v) {
    return __int_as_float(__builtin_amdgcn_mov_dpp(__float_as_int(v), 0x4E, 0xF, 0xF, true));
}
__device__ __forceinline__ float qpx3(float v) {
    return __int_as_float(__builtin_amdgcn_mov_dpp(__float_as_int(v), 0x1B, 0xF, 0xF, true));
}

// ===== K0: lane-ordered blob: blob4[q*80 + j] = {M[(kq*4+k)*80 + col(j)]}
// col(j) = (j&3)*20 + (j>>2) — the rec kernel's lane->col mapping BAKED IN,
// so rec's weight loads are lane-contiguous (stride 16B) off one base.
__global__ void wprep(const float* __restrict__ U1, const float* __restrict__ W2,
                      const float* __restrict__ U2, float4* __restrict__ blob) {
    int i = threadIdx.x + blockIdx.x * blockDim.x;
    if (i >= 15 * G4) return;
    int q = i / G4, j = i - q * G4;
    int m = q / 5, kq = q - m * 5;
    int col = (j & 3) * HH + (j >> 2);
    const float* M = (m == 0) ? U1 : (m == 1) ? W2 : U2;
    float4 v;
    v.x = M[(kq * 4 + 0) * G4 + col];
    v.y = M[(kq * 4 + 1) * G4 + col];
    v.z = M[(kq * 4 + 2) * G4 + col];
    v.w = M[(kq * 4 + 3) * G4 + col];
    blob[i] = v;
}

// ===== K1: xw[t][b][col] = b1[col] + sum_f x[b][t][f]*W1[f][col]; TC=128, 8-row tiles =====
__global__ __launch_bounds__(PBLK, 2) void proj_x(
    const float* __restrict__ x, const float* __restrict__ W1,
    const float* __restrict__ b1, float* __restrict__ xw, int B)
{
    __shared__ float xs[TC][FF + 4];   // 34.8 KB
    __shared__ float ws[FF][G4];       // 20 KB
    __shared__ float bs[G4];
    const int tid = threadIdx.x;
    const int b   = blockIdx.x >> 1;
    const int t0  = (blockIdx.x & 1) * TC;

    const float4* xg = (const float4*)(x + ((size_t)b * TT + t0) * FF);
    for (int i = tid; i < TC * FF / 4; i += PBLK) {
        int t = i >> 4, q = i & 15;
        *(float4*)&xs[t][q * 4] = xg[i];
    }
    const float4* wg = (const float4*)W1;
    float4* wsv = (float4*)ws;
    for (int i = tid; i < FF * G4 / 4; i += PBLK) wsv[i] = wg[i];
    if (tid < G4) bs[tid] = b1[tid];
    __syncthreads();

    const int colq = tid % 20;
    const int tq   = tid / 20;    // 0..15
    const int c0   = colq * 4;
    const int tb   = tq * 8;      // 8 rows per thread

    const float4 bias4 = *(const float4*)&bs[c0];
    float4 acc[8];
#pragma unroll
    for (int i = 0; i < 8; ++i) acc[i] = bias4;

#pragma unroll 8
    for (int f = 0; f < FF; ++f) {
        float4 wv = *(const float4*)&ws[f][c0];
#pragma unroll
        for (int r = 0; r < 8; ++r) {
            float xr = xs[tb + r][f];
            acc[r].x = fmaf(xr, wv.x, acc[r].x);
            acc[r].y = fmaf(xr, wv.y, acc[r].y);
            acc[r].z = fmaf(xr, wv.z, acc[r].z);
            acc[r].w = fmaf(xr, wv.w, acc[r].w);
        }
    }
#pragma unroll
    for (int i = 0; i < 8; ++i) {
        *(float4*)&xw[((size_t)(t0 + tb + i) * B + b) * G4 + c0] = acc[i];
    }
}

// ============ K2: producer-consumer recurrence (R5 structure), blob-sourced weights ============
__global__ __launch_bounds__(RBLK, 2) void lstm2_pc(
    const float* __restrict__ xw, const float4* __restrict__ blob,
    const float* __restrict__ b2,
    const float* __restrict__ Wd, const float* __restrict__ bd,
    float* __restrict__ out, int B)
{
    const int tid  = threadIdx.x;
    const bool isL1 = tid < 320;
    const int rt   = isL1 ? tid : tid - 320;
    const int elem = rt / G4;          // 0..3
    const int j    = rt - elem * G4;   // 0..79
    const int g    = j & 3;            // gate: 0=i 1=f 2=c 3=o
    const int u    = j >> 2;           // unit 0..19
    const int col  = g * HH + u;
    const int b0   = blockIdx.x * EPB;

    __shared__ float h1b[2][EPB][24];
    __shared__ float h2b[2][EPB][24];

    // R5-style pre-loop arrays; source = lane-ordered blob (coalesced dwordx4,
    // one base + imm offsets). Compiler may remat per-step — remat is now cheap.
    const float4* wb4 = blob + j;
    float wA[HH], wB[HH];
    if (isL1) {
#pragma unroll
        for (int q = 0; q < 5; ++q) {
            float4 v = wb4[q * G4];
            wA[4*q+0] = v.x; wA[4*q+1] = v.y; wA[4*q+2] = v.z; wA[4*q+3] = v.w;
        }
    } else {
#pragma unroll
        for (int q = 0; q < 5; ++q) {
            float4 v = wb4[(5 + q) * G4];
            wA[4*q+0] = v.x; wA[4*q+1] = v.y; wA[4*q+2] = v.z; wA[4*q+3] = v.w;
            float4 v2 = wb4[(10 + q) * G4];
            wB[4*q+0] = v2.x; wB[4*q+1] = v2.y; wB[4*q+2] = v2.z; wB[4*q+3] = v2.w;
        }
    }
    const float bias = isL1 ? 0.f : b2[col];

    for (int i = tid; i < 2 * EPB * 24; i += RBLK) ((float*)h1b)[i] = 0.f;
    for (int i = tid; i < 2 * EPB * 24; i += RBLK) ((float*)h2b)[i] = 0.f;

    const size_t tstride = (size_t)B * G4;
    const float* xwp = xw + (size_t)(b0 + elem) * G4 + col;
    float xwc = isL1 ? xwp[0] : 0.f;
    xwp += tstride;
    float c1 = 0.f, c2 = 0.f;
    __syncthreads();

    for (int i = 0; i <= TT; ++i) {
        const int rb = (i + 1) & 1;    // read buffers
        const int wb = i & 1;          // write buffers

        if (isL1 && i < TT) {
            float xwn = 0.f;
            if (i + 1 < TT) xwn = *xwp;
            xwp += tstride;

            // z = xw(i) + h1(i-1) @ U1
            float zz0 = 0.f, zz1 = 0.f, zz2 = 0.f, zz3 = 0.f;
            const float4* hv = (const float4*)h1b[rb][elem];
#pragma unroll
            for (int q = 0; q < HH / 4; ++q) {
                float4 hh = hv[q];
                zz0 = fmaf(hh.x, wA[4*q+0], zz0);
                zz1 = fmaf(hh.y, wA[4*q+1], zz1);
                zz2 = fmaf(hh.z, wA[4*q+2], zz2);
                zz3 = fmaf(hh.w, wA[4*q+3], zz3);
            }
            float z = xwc + ((zz0 + zz1) + (zz2 + zz3));

            float a = (g == 2) ? fmaxf(z, 0.f) : sigmoidf_(z);
            float a1 = qpx1(a), a2 = qpx2(a), a3 = qpx3(a);
            c1 = a1 * c1 + a * a2;
            float h1n = a3 * fmaxf(c1, 0.f);
            if (g == 0) h1b[wb][elem][u] = h1n;
            xwc = xwn;
        }
        if (!isL1 && i >= 1) {
            // z2 = b2 + h1(i-1) @ W2 + h2(i-2) @ U2
            float y0 = 0.f, y1 = 0.f, y2 = 0.f, y3 = 0.f;
            const float4* h1v = (const float4*)h1b[rb][elem];
            const float4* h2v = (const float4*)h2b[rb][elem];
#pragma unroll
            for (int q = 0; q < HH / 4; ++q) {
                float4 ha = h1v[q];
                float4 hb = h2v[q];
                y0 = fmaf(ha.x, wA[4*q+0], y0);
                y1 = fmaf(ha.y, wA[4*q+1], y1);
                y2 = fmaf(ha.z, wA[4*q+2], y2);
                y3 = fmaf(ha.w, wA[4*q+3], y3);
                y0 = fmaf(hb.x, wB[4*q+0], y0);
                y1 = fmaf(hb.y, wB[4*q+1], y1);
                y2 = fmaf(hb.z, wB[4*q+2], y2);
                y3 = fmaf(hb.w, wB[4*q+3], y3);
            }
            float z2v = bias + ((y0 + y1) + (y2 + y3));

            float bgt = (g == 2) ? fmaxf(z2v, 0.f) : sigmoidf_(z2v);
            float b1_ = qpx1(bgt), b2_ = qpx2(bgt), b3_ = qpx3(bgt);
            c2 = b1_ * c2 + bgt * b2_;
            float h2n = b3_ * fmaxf(c2, 0.f);
            if (g == 0) h2b[wb][elem][u] = h2n;
        }
        __syncthreads();
    }

    if (tid < EPB) {
        float acc = bd[0];
#pragma unroll
        for (int k = 0; k < HH; ++k) acc += h2b[0][tid][k] * Wd[k];
        out[b0 + tid] = acc;
    }
}

// ================= Fallback (ws too small): fused single kernel =================
__global__ __launch_bounds__(PBLK, 2) void lstm2_fused_fb(
    const float* __restrict__ x,
    const float* __restrict__ W1, const float* __restrict__ U1, const float* __restrict__ b1,
    const float* __restrict__ W2, const float* __restrict__ U2, const float* __restrict__ b2,
    const float* __restrict__ Wd, const float* __restrict__ bd,
    float* __restrict__ out)
{
    const int tid  = threadIdx.x;
    const int elem = tid / G4;
    const int j    = tid - elem * G4;
    const int g    = j & 3;
    const int u    = j >> 2;
    const int col  = g * HH + u;
    const int b0   = blockIdx.x * EPB;

    __shared__ float xs[2][EPB][FF];
    __shared__ float h1b[2][EPB][24];
    __shared__ float h2b[2][EPB][24];

    float w1[FF], u1[HH], w2[HH], u2[HH];
#pragma unroll
    for (int f = 0; f < FF; ++f) w1[f] = W1[f * G4 + col];
#pragma unroll
    for (int k = 0; k < HH; ++k) u1[k] = U1[k * G4 + col];
#pragma unroll
    for (int k = 0; k < HH; ++k) w2[k] = W2[k * G4 + col];
#pragma unroll
    for (int k = 0; k < HH; ++k) u2[k] = U2[k * G4 + col];
    const float bias1 = b1[col];
    const float bias2 = b2[col];

    for (int i = tid; i < 2 * EPB * 24; i += PBLK) ((float*)h1b)[i] = 0.f;
    for (int i = tid; i < 2 * EPB * 24; i += PBLK) ((float*)h2b)[i] = 0.f;
    if (tid < EPB * FF) {
        int e2 = tid >> 6, f2 = tid & 63;
        xs[0][e2][f2] = x[((long)(b0 + e2) * TT + 0) * FF + f2];
    }
    __syncthreads();

    float c1 = 0.f, c2 = 0.f;
    for (int t = 0; t < TT; ++t) {
        const int cur = t & 1;
        float xpre = 0.f;
        if (t + 1 < TT && tid < EPB * FF) {
            int e2 = tid >> 6, f2 = tid & 63;
            xpre = x[((long)(b0 + e2) * TT + (t + 1)) * FF + f2];
        }
        float zz0 = 0.f, zz1 = 0.f, zz2 = 0.f, zz3 = 0.f;
        const float4* xv = (const float4*)xs[cur][elem];
#pragma unroll
        for (int q = 0; q < FF / 4; ++q) {
            float4 xx = xv[q];
            zz0 = fmaf(xx.x, w1[4*q+0], zz0);
            zz1 = fmaf(xx.y, w1[4*q+1], zz1);
            zz2 = fmaf(xx.z, w1[4*q+2], zz2);
            zz3 = fmaf(xx.w, w1[4*q+3], zz3);
        }
        const float4* hv = (const float4*)h1b[cur][elem];
#pragma unroll
        for (int q = 0; q < HH / 4; ++q) {
            float4 hh = hv[q];
            zz0 = fmaf(hh.x, u1[4*q+0], zz0);
            zz1 = fmaf(hh.y, u1[4*q+1], zz1);
            zz2 = fmaf(hh.z, u1[4*q+2], zz2);
            zz3 = fmaf(hh.w, u1[4*q+3], zz3);
        }
        float z = bias1 + ((zz0 + zz1) + (zz2 + zz3));
        float a = (g == 2) ? fmaxf(z, 0.f) : sigmoidf_(z);
        float a1 = qpx1(a), a2 = qpx2(a), a3 = qpx3(a);
        c1 = a1 * c1 + a * a2;
        float h1n = a3 * fmaxf(c1, 0.f);
        if (g == 0) h1b[cur ^ 1][elem][u] = h1n;
        __syncthreads();
        if (t + 1 < TT && tid < EPB * FF) xs[cur ^ 1][tid >> 6][tid & 63] = xpre;

        float y0 = 0.f, y1 = 0.f, y2 = 0.f, y3 = 0.f;
        const float4* h1v = (const float4*)h1b[cur ^ 1][elem];
        const float4* h2v = (const float4*)h2b[cur][elem];
#pragma unroll
        for (int q = 0; q < HH / 4; ++q) {
            float4 ha = h1v[q];
            float4 hb = h2v[q];
            y0 = fmaf(ha.x, w2[4*q+0], y0);
            y1 = fmaf(ha.y, w2[4*q+1], y1);
            y2 = fmaf(ha.z, w2[4*q+2], y2);
            y3 = fmaf(ha.w, w2[4*q+3], y3);
            y0 = fmaf(hb.x, u2[4*q+0], y0);
            y1 = fmaf(hb.y, u2[4*q+1], y1);
            y2 = fmaf(hb.z, u2[4*q+2], y2);
            y3 = fmaf(hb.w, u2[4*q+3], y3);
        }
        float z2v = bias2 + ((y0 + y1) + (y2 + y3));
        float bgt = (g == 2) ? fmaxf(z2v, 0.f) : sigmoidf_(z2v);
        float b1_ = qpx1(bgt), b2_ = qpx2(bgt), b3_ = qpx3(bgt);
        c2 = b1_ * c2 + bgt * b2_;
        float h2n = b3_ * fmaxf(c2, 0.f);
        if (g == 0) h2b[cur ^ 1][elem][u] = h2n;
        __syncthreads();
    }
    if (j == 0) {
        float acc = bd[0];
#pragma unroll
        for (int k = 0; k < HH; ++k) acc += h2b[0][elem][k] * Wd[k];
        out[b0 + elem] = acc;
    }
}

extern "C" void kernel_launch(void* const* d_in, const int* in_sizes, int n_in,
                              void* d_out, int out_size, void* d_ws, size_t ws_size,
                              hipStream_t stream) {
    const float* x  = (const float*)d_in[0];
    const float* W1 = (const float*)d_in[1];
    const float* U1 = (const float*)d_in[2];
    const float* b1 = (const float*)d_in[3];
    const float* W2 = (const float*)d_in[4];
    const float* U2 = (const float*)d_in[5];
    const float* b2 = (const float*)d_in[6];
    const float* Wd = (const float*)d_in[7];
    const float* bd = (const float*)d_in[8];
    float* out = (float*)d_out;
    const int B = in_sizes[0] / (TT * FF);   // 2048

    const size_t need = (size_t)BLOB_BYTES + (size_t)B * TT * G4 * sizeof(float);
    if (ws_size >= need) {
        float4* blob = (float4*)d_ws;
        float*  xw   = (float*)((char*)d_ws + BLOB_BYTES);
        hipLaunchKernelGGL(wprep, dim3(5), dim3(256), 0, stream, U1, W2, U2, blob);
        hipLaunchKernelGGL(proj_x, dim3(B * (TT / TC)), dim3(PBLK), 0, stream,
                           x, W1, b1, xw, B);
        hipLaunchKernelGGL(lstm2_pc, dim3(B / EPB), dim3(RBLK), 0, stream,
                           xw, blob, b2, Wd, bd, out, B);
    } else {
        hipLaunchKernelGGL(lstm2_fused_fb, dim3(B / EPB), dim3(PBLK), 0, stream,
                           x, W1, U1, b1, W2, U2, b2, Wd, bd, out);
    }
}